// Round 3
// baseline (1388.382 us; speedup 1.0000x reference)
//
#include <hip/hip_runtime.h>

// ============================================================================
// DecoderGenerator: 2-layer LSTM decoder + additive attention + big vocab
// projection + NLL, fully fused on-device.
//
//   1. prep_kernel     : bf16-cast weights/enc/fcW, gather embeddings,
//                        transpose enc, init h-state buffers, zero flags.
//   2. a0_kernel       : A0 = xs @ W_ih0^T + b  (hoisted layer-0 input GEMM)
//   3. lstm_kernel     : persistent 32-WG x 512-thread kernel.
//                        ROUND 8: L0/L1 halves fully decoupled (no
//                        __syncthreads in loop). Private LDS barriers per
//                        half; 3 flag sets (flag0 = h0 done, flag1 = h1 done,
//                        flagS1 = L1 stage done) so L0's h0 critical loop
//                        never waits on L1 compute. Lane-consecutive staging
//                        (bank-conflict-free), split MFMA chains.
//   4. phpe_kernel     : ph = Hall@Wh^T ; pe = enc@We^T + attn_b
//   5. logits_kernel   : logits[t,b,l] = sum_k v_w[k] tanh(ph+pe)
//   6. att_kernel      : softmax over b (axis=1 of (T,B,L) — per reference!)
//   7. weighted_kernel : weighted = att @ enc  (per-batch GEMM) -> G[:,512:]
//   8. fc_kernel       : m97-structure 128x128xBK64 tiled GEMM + fused
//                        per-row (max,sumexp) partials.
//   9. tgt_kernel      : target logits z_y per row
//  10. finalize_kernel : logsumexp merge + masked-mean NLL -> d_out[0]
// ============================================================================

#define DI __device__ __forceinline__

typedef __attribute__((ext_vector_type(8))) short short8;
typedef __attribute__((ext_vector_type(4))) float floatx4;

#define TSEQ   128
#define VOCAB  32000
#define GDIM   2048   // 4*H
#define NROW   2048   // B*T
#define KFC    1024   // 2*H
#define HPAD   520    // LDS row stride for h staging (512 + 8 pad)

// ---------------- small helpers ----------------
DI float bf2f(unsigned short u) {
    union { unsigned u; float f; } x; x.u = ((unsigned)u) << 16; return x.f;
}
DI unsigned short f2bf(float f) {   // RNE float -> bf16
    unsigned u = __float_as_uint(f);
    unsigned r = (u + 0x7FFF + ((u >> 16) & 1)) >> 16;
    return (unsigned short)r;
}
DI short8 ld8(const unsigned short* p) { return *(const short8*)p; }
DI floatx4 mfma16(short8 a, short8 b, floatx4 c) {
    return __builtin_amdgcn_mfma_f32_16x16x32_bf16(a, b, c, 0, 0, 0);
}
DI float sigm(float x) { return __builtin_amdgcn_rcpf(1.f + __expf(-x)); }
DI float tanh_f(float x) {
    float xc = fminf(8.f, fmaxf(-8.f, x));
    float e  = __expf(2.f * xc);
    return (e - 1.f) * __builtin_amdgcn_rcpf(e + 1.f);
}

// async global -> LDS, 16B per lane. LDS dest must be wave-uniform base;
// lane l writes base + l*16. Global src is per-lane.
#define GLD16(gsrc, ldst)                                                     \
    __builtin_amdgcn_global_load_lds(                                         \
        (const __attribute__((address_space(1))) unsigned int*)(gsrc),        \
        (__attribute__((address_space(3))) unsigned int*)(ldst), 16, 0, 0)

// fallback path: make the failure visible instead of faulting
__global__ void zero_out_kernel(float* out, int n) {
    int i = blockIdx.x * 64 + threadIdx.x;
    if (i < n) out[i] = 0.f;
}

// ============================================================================
// 1. prep kernel : segmented grid-stride over all conversion jobs
// ============================================================================
__global__ void prep_kernel(const int* X, const float* enc, const float* emb,
                            const float* Wih0, const float* Whh0,
                            const float* Wih1, const float* Whh1,
                            const float* attnW, const float* h0,
                            const float* fcW,
                            unsigned short* wih0b, unsigned short* whh0b,
                            unsigned short* wih1b, unsigned short* whh1b,
                            unsigned short* whb, unsigned short* web,
                            unsigned short* encb, unsigned short* enctb,
                            unsigned short* xsb,
                            unsigned short* h0buf, unsigned short* h1buf,
                            unsigned short* fcWb,
                            int* ctrl) {
    if (blockIdx.x == 0) {              // zero all 3072 flag ints
#pragma unroll
        for (int j = 0; j < 12; ++j) ctrl[threadIdx.x + 256 * j] = 0;
    }
    long i = (long)blockIdx.x * 256 + threadIdx.x;
    const long NW = 1048576;
    const long NA = 262144;            // 512x512 half of attn_W
    if (i < NW) { wih0b[i] = f2bf(Wih0[i]); return; } i -= NW;
    if (i < NW) { whh0b[i] = f2bf(Whh0[i]); return; } i -= NW;
    if (i < NW) { wih1b[i] = f2bf(Wih1[i]); return; } i -= NW;
    if (i < NW) { whh1b[i] = f2bf(Whh1[i]); return; } i -= NW;
    if (i < NA) { long k = i >> 9, h = i & 511; whb[i] = f2bf(attnW[k * 1024 + h]);       return; } i -= NA;
    if (i < NA) { long k = i >> 9, h = i & 511; web[i] = f2bf(attnW[k * 1024 + 512 + h]); return; } i -= NA;
    if (i < NW) { encb[i] = f2bf(enc[i]); return; } i -= NW;
    if (i < NW) {  // enc_t[b][h][l] = enc[b][l][h]
        long b = i >> 16, r = i & 65535, h = r >> 7, l = r & 127;
        enctb[i] = f2bf(enc[(b * 128 + l) * 512 + h]); return;
    } i -= NW;
    if (i < NW) {  // xs[t*16+b][e] = emb[X[b][t]][e]
        long m = i >> 9, e = i & 511, t = m >> 4, b = m & 15;
        int xi = X[b * 129 + t];
        xi = (xi < 0) ? 0 : ((xi >= VOCAB) ? VOCAB - 1 : xi);   // defensive
        xsb[i] = f2bf(emb[(long)xi * 512 + e]); return;
    } i -= NW;
    if (i < 16384) {  // h inits into parity-1 buffers
        long layer = i >> 13, r = i & 8191;
        unsigned short v = f2bf(h0[layer * 8192 + r]);
        if (layer == 0) h0buf[8192 + r] = v; else h1buf[8192 + r] = v;
        return;
    } i -= 16384;
    if (i < 8192000) {  // fcW f32 -> bf16, 4 elements per thread
        float4 v = ((const float4*)fcW)[i];
        ushort4 o;
        o.x = f2bf(v.x); o.y = f2bf(v.y); o.z = f2bf(v.z); o.w = f2bf(v.w);
        ((ushort4*)fcWb)[i] = o;
    }
}

// ============================================================================
// shared 64x64 MFMA tile: C[m0..+63][n0..+63] += A(m,k) * B(n,k)^T
// ============================================================================
DI void gemm64_acc(const unsigned short* A, const unsigned short* Bw,
                   int m0, int n0, int lda, int ldb, int nkb, floatx4 acc[4]) {
    int tid = threadIdx.x;
    int wv = tid >> 6, ln = tid & 63;
    int colL = ln & 15, koff = (ln >> 4) * 8;
    const unsigned short* ar  = A  + (size_t)(m0 + wv * 16 + colL) * lda + koff;
    const unsigned short* br0 = Bw + (size_t)(n0 +  0 + colL) * ldb + koff;
    const unsigned short* br1 = Bw + (size_t)(n0 + 16 + colL) * ldb + koff;
    const unsigned short* br2 = Bw + (size_t)(n0 + 32 + colL) * ldb + koff;
    const unsigned short* br3 = Bw + (size_t)(n0 + 48 + colL) * ldb + koff;
    for (int kb = 0; kb < nkb; ++kb) {
        short8 af = ld8(ar + kb * 32);
        acc[0] = mfma16(af, ld8(br0 + kb * 32), acc[0]);
        acc[1] = mfma16(af, ld8(br1 + kb * 32), acc[1]);
        acc[2] = mfma16(af, ld8(br2 + kb * 32), acc[2]);
        acc[3] = mfma16(af, ld8(br3 + kb * 32), acc[3]);
    }
}

// 2. A0 = xs @ W_ih0^T + (b_ih0 + b_hh0), stored bf16 (bias folded)
__global__ void a0_kernel(const unsigned short* xs, const unsigned short* wih0b,
                          const float* bih0, const float* bhh0, unsigned short* A0b) {
    floatx4 acc[4] = {{0,0,0,0},{0,0,0,0},{0,0,0,0},{0,0,0,0}};
    int m0 = blockIdx.x * 64, n0 = blockIdx.y * 64;
    gemm64_acc(xs, wih0b, m0, n0, 512, 512, 16, acc);
    int tid = threadIdx.x, wv = tid >> 6, ln = tid & 63, colL = ln & 15, q = ln >> 4;
    int mrow = m0 + wv * 16;
#pragma unroll
    for (int nt = 0; nt < 4; ++nt) {
        int col = n0 + nt * 16 + colL;
        float bb = bih0[col] + bhh0[col];
#pragma unroll
        for (int r = 0; r < 4; ++r)
            A0b[(size_t)(mrow + q * 4 + r) * GDIM + col] = f2bf(acc[nt][r] + bb);
    }
}

// ============================================================================
// 3. persistent LSTM kernel.  32 WGs x 512 threads.
//    ROUND 8: decoupled halves.
//      flags[w*32]          = flag0: L0 finished tick t  (value t+1)
//      flags[1024 + w*32]   = flag1: L1 finished step s  (value s+1 = t)
//      flags[2048 + w*32]   = flagS1: L1 finished STAGING its tick t (value t)
//    L0 tick t (0..127):  wait flag0>=t, flagS1>=t-1; stage h0[t-1]->hshA;
//      barA; 2-chain MFMA; barB; elementwise; store h0[t]; vmcnt drain;
//      publish flag0=t+1; prefetch A0[t+1].
//    L1 tick t (1..128):  wait flag0>=t, flag1>=t-1; stage h0[t-1]->hshB,
//      h1[t-2]->hsh1; barA; publish flagS1=t; 4-chain MFMA; barB;
//      elementwise; store h1[t-1]+Hall+Gmat; vmcnt drain; publish flag1=t.
//    Parity-overwrite safety: every h0/h1 buffer write is gated (via the
//    flag waits above) behind every reader's completed stage of that parity.
// ============================================================================
__global__ __launch_bounds__(512, 1)
void lstm_kernel(const unsigned short* A0b,
                 const unsigned short* whh0b, const unsigned short* wih1b,
                 const unsigned short* whh1b,
                 const float* bih1, const float* bhh1, const float* c0in,
                 unsigned short* h0buf, unsigned short* h1buf,
                 unsigned short* Hall, unsigned short* Gmat, int* flags) {
    __shared__ unsigned short hshA[16 * HPAD];   // L0's copy of h0[t-1]
    __shared__ unsigned short hshB[16 * HPAD];   // L1's copy of h0[t-1]
    __shared__ unsigned short hsh1[16 * HPAD];   // L1's h1[t-2]
    __shared__ float gbuf[2][4][16][17];         // [half][gate][batch][unit]
    __shared__ int cnt[8];                       // 0..2: L0 barA/barB/pub; 3..5: L1
    int wg = blockIdx.x;            // 0..31
    int tid = threadIdx.x;          // 0..511
    int half = tid >> 8;            // 0 = L0, 1 = L1
    int lt   = tid & 255;
    int wv = lt >> 6, ln = lt & 63;
    int u0 = wg * 16;
    int n0 = wv * 512 + u0;         // gate column base (wave-of-half = gate)
    int colL = ln & 15, q = ln >> 4, koff = q * 8;
    int eb = lt >> 4, eu = lt & 15; // elementwise mapping within half
    float c = c0in[half * 8192 + eb * 512 + u0 + eu];
    float bias1 = (half == 1) ? (bih1[n0 + colL] + bhh1[n0 + colL]) : 0.f;

    if (tid < 8) cnt[tid] = 0;

    // ---- one-time: weight slices into registers ----
    short8 wA[16], wB[16];
    if (half == 0) {
        const unsigned short* wr0 = whh0b + (size_t)(n0 + colL) * 512 + koff;
#pragma unroll
        for (int kb = 0; kb < 16; ++kb) wA[kb] = ld8(wr0 + kb * 32);
#pragma unroll
        for (int kb = 0; kb < 16; ++kb) wB[kb] = wA[kb];   // unused, keep defined
    } else {
        const unsigned short* wr1 = wih1b + (size_t)(n0 + colL) * 512 + koff;
        const unsigned short* wr2 = whh1b + (size_t)(n0 + colL) * 512 + koff;
#pragma unroll
        for (int kb = 0; kb < 16; ++kb) wA[kb] = ld8(wr1 + kb * 32);
#pragma unroll
        for (int kb = 0; kb < 16; ++kb) wB[kb] = ld8(wr2 + kb * 32);
    }
    __syncthreads();   // cnt[] zero + weights resident before any arrive

    // stage 16KB (8 x 8B per thread, lane-consecutive -> conflict-free)
    auto stage16k = [&](const unsigned short* src, unsigned short* dst) {
        const unsigned long long* s = (const unsigned long long*)src;
        unsigned long long v[8];
#pragma unroll
        for (int k = 0; k < 8; ++k)
            v[k] = __hip_atomic_load(s + lt + 256 * k, __ATOMIC_RELAXED,
                                     __HIP_MEMORY_SCOPE_AGENT);
#pragma unroll
        for (int k = 0; k < 8; ++k) {
            int u = lt + 256 * k;
            *(unsigned long long*)&dst[(u >> 7) * HPAD + (u & 127) * 4] = v[k];
        }
    };
    // intra-half barrier: monotonic LDS counter, 4 waves
    auto bar = [&](int idx, int target) {
        asm volatile("s_waitcnt lgkmcnt(0)" ::: "memory");
        if (ln == 0)
            __hip_atomic_fetch_add(&cnt[idx], 1, __ATOMIC_RELAXED,
                                   __HIP_MEMORY_SCOPE_WORKGROUP);
        int g = 0;
        while (__hip_atomic_load(&cnt[idx], __ATOMIC_RELAXED,
                                 __HIP_MEMORY_SCOPE_WORKGROUP) < target) {
            if (++g > (1 << 22)) break;
        }
        asm volatile("" ::: "memory");
    };
    // combined dual-flag poll: lanes 0..31 poll fa>=ta, lanes 32..63 fb>=tb
    auto poll2 = [&](int* fa, int ta, int* fb, int tb) {
        int m = ln & 31;
        int* f = (ln < 32) ? fa + m * 32 : fb + m * 32;
        int tg = (ln < 32) ? ta : tb;
        int g = 0;
        while (__hip_atomic_load(f, __ATOMIC_RELAXED,
                                 __HIP_MEMORY_SCOPE_AGENT) < tg) {
            __builtin_amdgcn_s_sleep(1);
            if (++g > (1 << 22)) break;
        }
        asm volatile("" ::: "memory");
    };

    if (half == 0) {
        // =================== L0 half ===================
        floatx4 a0pre;
        {
            const unsigned short* a0r = A0b + n0 + colL;
            a0pre[0] = bf2f(a0r[(q * 4 + 0) * GDIM]);
            a0pre[1] = bf2f(a0r[(q * 4 + 1) * GDIM]);
            a0pre[2] = bf2f(a0r[(q * 4 + 2) * GDIM]);
            a0pre[3] = bf2f(a0r[(q * 4 + 3) * GDIM]);
        }
#pragma unroll 1
        for (int t = 0; t < TSEQ; ++t) {
            poll2(flags, t, flags + 2048, t - 1);
            stage16k(h0buf + ((t - 1) & 1) * 8192, hshA);
            bar(0, 4 * (t + 1));
            // MFMA: 2 independent 8-chains
            const unsigned short* hl0 = hshA + colL * HPAD + koff;
            floatx4 c0v = a0pre, c1v = {0, 0, 0, 0};
#pragma unroll
            for (int kb = 0; kb < 8; ++kb) {
                c0v = mfma16(ld8(hl0 + (2 * kb) * 32),     wA[2 * kb],     c0v);
                c1v = mfma16(ld8(hl0 + (2 * kb + 1) * 32), wA[2 * kb + 1], c1v);
            }
            floatx4 acc = c0v + c1v;
            gbuf[0][wv][q * 4 + 0][colL] = acc[0];
            gbuf[0][wv][q * 4 + 1][colL] = acc[1];
            gbuf[0][wv][q * 4 + 2][colL] = acc[2];
            gbuf[0][wv][q * 4 + 3][colL] = acc[3];
            bar(1, 4 * (t + 1));
            // elementwise -> h0[t]
            float gi = gbuf[0][0][eb][eu], gf = gbuf[0][1][eb][eu];
            float gg = gbuf[0][2][eb][eu], go = gbuf[0][3][eb][eu];
            float c2 = sigm(gf) * c + sigm(gi) * tanh_f(gg);
            float h2 = sigm(go) * tanh_f(c2);
            c = c2;
            unsigned hb = (unsigned)f2bf(h2);
            unsigned up = __shfl_down(hb, 1, 64);
            if ((eu & 1) == 0)
                __hip_atomic_store(
                    (unsigned*)(h0buf + (t & 1) * 8192 + eb * 512 + u0 + eu),
                    hb | (up << 16), __ATOMIC_RELAXED, __HIP_MEMORY_SCOPE_AGENT);
            asm volatile("s_waitcnt vmcnt(0)" ::: "memory");
            if (ln == 0)
                __hip_atomic_fetch_add(&cnt[2], 1, __ATOMIC_RELAXED,
                                       __HIP_MEMORY_SCOPE_WORKGROUP);
            if (tid == 0) {
                int g = 0;
                while (__hip_atomic_load(&cnt[2], __ATOMIC_RELAXED,
                                         __HIP_MEMORY_SCOPE_WORKGROUP) < 4 * (t + 1)) {
                    if (++g > (1 << 22)) break;
                }
                asm volatile("" ::: "memory");
                __hip_atomic_store(flags + wg * 32, t + 1,
                                   __ATOMIC_RELAXED, __HIP_MEMORY_SCOPE_AGENT);
            }
            // prefetch next tick's A0 (overlaps the next poll window)
            if (t + 1 < TSEQ) {
                const unsigned short* a0r = A0b + (size_t)((t + 1) * 16) * GDIM + n0 + colL;
                a0pre[0] = bf2f(a0r[(q * 4 + 0) * GDIM]);
                a0pre[1] = bf2f(a0r[(q * 4 + 1) * GDIM]);
                a0pre[2] = bf2f(a0r[(q * 4 + 2) * GDIM]);
                a0pre[3] = bf2f(a0r[(q * 4 + 3) * GDIM]);
            }
        }
    } else {
        // =================== L1 half ===================
#pragma unroll 1
        for (int t = 1; t <= TSEQ; ++t) {
            poll2(flags, t, flags + 1024, t - 1);
            stage16k(h0buf + ((t - 1) & 1) * 8192, hshB);
            stage16k(h1buf + ((t - 2) & 1) * 8192, hsh1);
            bar(3, 4 * t);
            if (tid == 256)
                __hip_atomic_store(flags + 2048 + wg * 32, t,
                                   __ATOMIC_RELAXED, __HIP_MEMORY_SCOPE_AGENT);
            // MFMA: 4 independent 8-chains
            const unsigned short* hl0 = hshB + colL * HPAD + koff;
            const unsigned short* hl1 = hsh1 + colL * HPAD + koff;
            floatx4 a0c = {bias1, bias1, bias1, bias1};
            floatx4 a1c = {0, 0, 0, 0}, b0c = {0, 0, 0, 0}, b1c = {0, 0, 0, 0};
#pragma unroll
            for (int kb = 0; kb < 8; ++kb) {
                a0c = mfma16(ld8(hl0 + (2 * kb) * 32),     wA[2 * kb],     a0c);
                a1c = mfma16(ld8(hl0 + (2 * kb + 1) * 32), wA[2 * kb + 1], a1c);
                b0c = mfma16(ld8(hl1 + (2 * kb) * 32),     wB[2 * kb],     b0c);
                b1c = mfma16(ld8(hl1 + (2 * kb + 1) * 32), wB[2 * kb + 1], b1c);
            }
            floatx4 acc = (a0c + a1c) + (b0c + b1c);
            gbuf[1][wv][q * 4 + 0][colL] = acc[0];
            gbuf[1][wv][q * 4 + 1][colL] = acc[1];
            gbuf[1][wv][q * 4 + 2][colL] = acc[2];
            gbuf[1][wv][q * 4 + 3][colL] = acc[3];
            bar(4, 4 * t);
            // elementwise -> h1[t-1]
            float gi = gbuf[1][0][eb][eu], gf = gbuf[1][1][eb][eu];
            float gg = gbuf[1][2][eb][eu], go = gbuf[1][3][eb][eu];
            float c2 = sigm(gf) * c + sigm(gi) * tanh_f(gg);
            float h2 = sigm(go) * tanh_f(c2);
            c = c2;
            unsigned hb = (unsigned)f2bf(h2);
            unsigned up = __shfl_down(hb, 1, 64);
            int s = t - 1;
            if ((eu & 1) == 0) {
                unsigned packed = hb | (up << 16);
                __hip_atomic_store(
                    (unsigned*)(h1buf + (s & 1) * 8192 + eb * 512 + u0 + eu),
                    packed, __ATOMIC_RELAXED, __HIP_MEMORY_SCOPE_AGENT);
                *(unsigned*)&Hall[(size_t)(s * 16 + eb) * 512 + u0 + eu] = packed;
                *(unsigned*)&Gmat[(size_t)(eb * 128 + s) * KFC + u0 + eu] = packed;
            }
            asm volatile("s_waitcnt vmcnt(0)" ::: "memory");
            if (ln == 0)
                __hip_atomic_fetch_add(&cnt[5], 1, __ATOMIC_RELAXED,
                                       __HIP_MEMORY_SCOPE_WORKGROUP);
            if (tid == 256) {
                int g = 0;
                while (__hip_atomic_load(&cnt[5], __ATOMIC_RELAXED,
                                         __HIP_MEMORY_SCOPE_WORKGROUP) < 4 * t) {
                    if (++g > (1 << 22)) break;
                }
                asm volatile("" ::: "memory");
                __hip_atomic_store(flags + 1024 + wg * 32, t,
                                   __ATOMIC_RELAXED, __HIP_MEMORY_SCOPE_AGENT);
            }
        }
    }
}

// 4. ph = Hall @ Wh^T ; pe = enc @ We^T + attn_b   (z selects)
__global__ void phpe_kernel(const unsigned short* Hall, const unsigned short* encb,
                            const unsigned short* whb, const unsigned short* web,
                            const float* attnb, float* ph, float* pe) {
    bool ispe = (blockIdx.z != 0);
    const unsigned short* A  = ispe ? encb : Hall;
    const unsigned short* Bw = ispe ? web  : whb;
    float* out = ispe ? pe : ph;
    floatx4 acc[4] = {{0,0,0,0},{0,0,0,0},{0,0,0,0},{0,0,0,0}};
    int m0 = blockIdx.x * 64, n0 = blockIdx.y * 64;
    gemm64_acc(A, Bw, m0, n0, 512, 512, 16, acc);
    int tid = threadIdx.x, wv = tid >> 6, ln = tid & 63, colL = ln & 15, q = ln >> 4;
    int mrow = m0 + wv * 16;
#pragma unroll
    for (int nt = 0; nt < 4; ++nt) {
        int col = n0 + nt * 16 + colL;
        float bb = ispe ? attnb[col] : 0.f;
#pragma unroll
        for (int r = 0; r < 4; ++r)
            out[(size_t)(mrow + q * 4 + r) * 512 + col] = acc[nt][r] + bb;
    }
}

// 5. logits[t][l][b] = sum_k v_w[k] * tanh(ph[t*16+b][k] + pe[b*128+l][k])
__global__ void logits_kernel(const float* ph, const float* pe, const float* vw,
                              float* logits) {
    int m = blockIdx.x;             // t*16+b
    int t = m >> 4, b = m & 15;
    int tid = threadIdx.x, wv = tid >> 6, ln = tid & 63;
    const float* phr = ph + (size_t)m * 512 + ln * 8;
    floatx4 ph0 = *(const floatx4*)phr;
    floatx4 ph1 = *(const floatx4*)(phr + 4);
    const float* vwr = vw + ln * 8;
    floatx4 vw0 = *(const floatx4*)vwr;
    floatx4 vw1 = *(const floatx4*)(vwr + 4);
    for (int li = 0; li < 32; ++li) {
        int ll = wv * 32 + li;
        const float* per = pe + (size_t)(b * 128 + ll) * 512 + ln * 8;
        floatx4 p0 = *(const floatx4*)per;
        floatx4 p1 = *(const floatx4*)(per + 4);
        float s = 0.f;
#pragma unroll
        for (int j = 0; j < 4; ++j) s += vw0[j] * tanh_f(ph0[j] + p0[j]);
#pragma unroll
        for (int j = 0; j < 4; ++j) s += vw1[j] * tanh_f(ph1[j] + p1[j]);
#pragma unroll
        for (int off = 32; off; off >>= 1) s += __shfl_xor(s, off, 64);
        if (ln == 0) logits[((size_t)t * 128 + ll) * 16 + b] = s;
    }
}

// 6. softmax over b (axis=1 of (T,B,L)) -> att_bf16[b][t][l]
__global__ void att_kernel(const float* logits, unsigned short* attb) {
    int t = blockIdx.x, l = threadIdx.x;     // 128 threads
    const float* p = logits + ((size_t)t * 128 + l) * 16;
    float x[16], mx = -1e30f;
#pragma unroll
    for (int j = 0; j < 16; ++j) { x[j] = p[j]; mx = fmaxf(mx, x[j]); }
    float s = 0.f;
#pragma unroll
    for (int j = 0; j < 16; ++j) { x[j] = __expf(x[j] - mx); s += x[j]; }
    float inv = __builtin_amdgcn_rcpf(s);
#pragma unroll
    for (int j = 0; j < 16; ++j)
        attb[((size_t)j * 128 + t) * 128 + l] = f2bf(x[j] * inv);
}

// 7. weighted[b][t][h] = att[b] @ enc[b]  ->  G[b*128+t][512+h]
__global__ void weighted_kernel(const unsigned short* attb, const unsigned short* enctb,
                                unsigned short* Gmat) {
    int b = blockIdx.z;
    floatx4 acc[4] = {{0,0,0,0},{0,0,0,0},{0,0,0,0},{0,0,0,0}};
    int m0 = blockIdx.x * 64, n0 = blockIdx.y * 64;
    gemm64_acc(attb + (size_t)b * 128 * 128, enctb + (size_t)b * 512 * 128,
               m0, n0, 128, 128, 4, acc);
    int tid = threadIdx.x, wv = tid >> 6, ln = tid & 63, colL = ln & 15, q = ln >> 4;
    int mrow = m0 + wv * 16;
#pragma unroll
    for (int nt = 0; nt < 4; ++nt) {
        int col = n0 + nt * 16 + colL;
#pragma unroll
        for (int r = 0; r < 4; ++r)
            Gmat[(size_t)(b * 128 + mrow + q * 4 + r) * KFC + 512 + col] = f2bf(acc[nt][r]);
    }
}

// ============================================================================
// 8. fc GEMM (m97-structure) + fused per-row (max, sumexp) partials.
// ============================================================================
__global__ __launch_bounds__(256)
void fc_kernel(const unsigned short* G, const unsigned short* fcWb,
               const float* fcb, float2* partials) {
    __shared__ __align__(16) unsigned short lA[128 * 64];
    __shared__ __align__(16) unsigned short lB[128 * 64];
    __shared__ float2 pbuf[128][2];
    int nwg = blockIdx.x;            // 0..249
    int mwg = blockIdx.y;            // 0..15
    int n_base = nwg * 128, m_base = mwg * 128;
    int tid = threadIdx.x, wv = tid >> 6, l = tid & 63;
    int wr = wv >> 1, wc = wv & 1;
    int colL = l & 15, q16 = l >> 4, koff = q16 * 8;
    int srow = l >> 3, scol = (l & 7) * 8;     // staging sub-pattern per chunk

    floatx4 acc[4][4];
#pragma unroll
    for (int i = 0; i < 4; ++i)
#pragma unroll
        for (int j = 0; j < 4; ++j) acc[i][j] = (floatx4){0, 0, 0, 0};

    const unsigned short* gA = G    + (size_t)m_base * KFC;
    const unsigned short* gB = fcWb + (size_t)n_base * KFC;

    for (int kt = 0; kt < 16; ++kt) {
        if (kt) __syncthreads();     // previous tile's reads done before overwrite
        int k0 = kt * 64;
#pragma unroll
        for (int j = 0; j < 4; ++j) {
            int c = wv * 4 + j;
            const unsigned short* ga = gA + (size_t)(c * 8 + srow) * KFC + k0 + scol;
            const unsigned short* gb = gB + (size_t)(c * 8 + srow) * KFC + k0 + scol;
            GLD16(ga, lA + c * 512);
            GLD16(gb, lB + c * 512);
        }
        __syncthreads();             // barrier drains vmcnt -> tiles resident
#pragma unroll
        for (int ks = 0; ks < 2; ++ks) {
            const unsigned short* ap = lA + (wr * 64 + colL) * 64 + ks * 32 + koff;
            const unsigned short* bp = lB + (wc * 64 + colL) * 64 + ks * 32 + koff;
            short8 aF[4], bF[4];
#pragma unroll
            for (int ma = 0; ma < 4; ++ma) aF[ma] = ld8(ap + ma * 16 * 64);
#pragma unroll
            for (int nb = 0; nb < 4; ++nb) bF[nb] = ld8(bp + nb * 16 * 64);
#pragma unroll
            for (int ma = 0; ma < 4; ++ma)
#pragma unroll
                for (int nb = 0; nb < 4; ++nb)
                    acc[ma][nb] = mfma16(aF[ma], bF[nb], acc[ma][nb]);
        }
    }

    // ---- epilogue: per-row (max, sumexp) over this WG's 128 cols ----
    float cb[4];
#pragma unroll
    for (int nb = 0; nb < 4; ++nb)
        cb[nb] = fcb[n_base + wc * 64 + nb * 16 + colL];

#pragma unroll
    for (int ma = 0; ma < 4; ++ma) {
#pragma unroll
        for (int r = 0; r < 4; ++r) {
            float v0 = acc[ma][0][r] + cb[0];
            float v1 = acc[ma][1][r] + cb[1];
            float v2 = acc[ma][2][r] + cb[2];
            float v3 = acc[ma][3][r] + cb[3];
            float M = fmaxf(fmaxf(v0, v1), fmaxf(v2, v3));
#pragma unroll
            for (int off = 1; off < 16; off <<= 1) M = fmaxf(M, __shfl_xor(M, off, 64));
            float e = __expf(v0 - M) + __expf(v1 - M) + __expf(v2 - M) + __expf(v3 - M);
#pragma unroll
            for (int off = 1; off < 16; off <<= 1) e += __shfl_xor(e, off, 64);
            if (colL == 0)
                pbuf[wr * 64 + ma * 16 + q16 * 4 + r][wc] = make_float2(M, e);
        }
    }
    __syncthreads();
    if (tid < 128) {    // merge the two col-halves, write global partial
        float2 a = pbuf[tid][0], b = pbuf[tid][1];
        float M = fmaxf(a.x, b.x);
        float S = a.y * __expf(a.x - M) + b.y * __expf(b.x - M);
        partials[(size_t)(m_base + tid) * 250 + nwg] = make_float2(M, S);
    }
}

// 9. target logit per row: z_y = G[r] . fc_W[y] + fc_b[y]
__global__ void tgt_kernel(const unsigned short* G, const float* fcW, const float* fcb,
                           const int* X, float* tgt) {
    int r = blockIdx.x * 4 + (threadIdx.x >> 6);
    int ln = threadIdx.x & 63;
    int b = r >> 7, t = r & 127;
    int y = X[b * 129 + t + 1];
    y = (y < 0) ? 0 : ((y >= VOCAB) ? VOCAB - 1 : y);   // defensive
    const unsigned short* g = G + (size_t)r * KFC;
    const float* w = fcW + (size_t)y * KFC;
    float s = 0.f;
    for (int j = ln; j < KFC; j += 64) s += bf2f(g[j]) * w[j];
#pragma unroll
    for (int off = 32; off; off >>= 1) s += __shfl_xor(s, off, 64);
    if (ln == 0) tgt[r] = s + fcb[y];
}

// 10. merge partials -> logsumexp -> masked mean NLL
__global__ void finalize_kernel(const float2* partials, const float* tgt,
                                const int* X, float* out) {
    int tid = threadIdx.x;
    float vs = 0.f, vc = 0.f;
    for (int r = tid; r < NROW; r += 256) {
        const float2* p = partials + (size_t)r * 250;
        float M = p[0].x, S = p[0].y;
        for (int i = 1; i < 250; ++i) {
            float2 qq = p[i];
            float nm = fmaxf(M, qq.x);
            S = S * __expf(M - nm) + qq.y * __expf(qq.x - nm);
            M = nm;
        }
        float lse = M + __logf(S);
        int b = r >> 7, t = r & 127;
        int y = X[b * 129 + t + 1];
        if (y != 0) { vs += lse - tgt[r]; vc += 1.f; }
    }
    __shared__ float sv[256], sc[256];
    sv[tid] = vs; sc[tid] = vc;
    __syncthreads();
    for (int s = 128; s; s >>= 1) {
        if (tid < s) { sv[tid] += sv[tid + s]; sc[tid] += sc[tid + s]; }
        __syncthreads();
    }
    if (tid == 0) out[0] = sv[0] / sc[0];
}

// ============================================================================
// launcher
// ============================================================================
extern "C" void kernel_launch(void* const* d_in, const int* in_sizes, int n_in,
                              void* d_out, int out_size, void* d_ws, size_t ws_size,
                              hipStream_t stream) {
    const int*   X     = (const int*)d_in[0];
    const float* enc   = (const float*)d_in[2];
    const float* emb   = (const float*)d_in[3];
    const float* Wih0  = (const float*)d_in[4];
    const float* Whh0  = (const float*)d_in[5];
    const float* bih0  = (const float*)d_in[6];
    const float* bhh0  = (const float*)d_in[7];
    const float* Wih1  = (const float*)d_in[8];
    const float* Whh1  = (const float*)d_in[9];
    const float* bih1  = (const float*)d_in[10];
    const float* bhh1  = (const float*)d_in[11];
    const float* attnW = (const float*)d_in[12];
    const float* attnb = (const float*)d_in[13];
    const float* vw    = (const float*)d_in[14];
    const float* fcW   = (const float*)d_in[15];
    const float* fcb   = (const float*)d_in[16];
    const float* h0    = (const float*)d_in[17];
    const float* c0    = (const float*)d_in[18];

    char* ws = (char*)d_ws;
    size_t off = 0;
    auto take = [&](size_t bytes) { char* p = ws + off; off += (bytes + 255) & ~(size_t)255; return p; };
    int*            ctrl    = (int*)           take(12288);
    unsigned short* wih0b   = (unsigned short*)take(2097152);
    unsigned short* whh0b   = (unsigned short*)take(2097152);
    unsigned short* wih1b   = (unsigned short*)take(2097152);
    unsigned short* whh1b   = (unsigned short*)take(2097152);
    unsigned short* whb     = (unsigned short*)take(524288);
    unsigned short* web     = (unsigned short*)take(524288);
    unsigned short* encb    = (unsigned short*)take(2097152);
    unsigned short* enctb   = (unsigned short*)take(2097152);
    unsigned short* xsb     = (unsigned short*)take(2097152);
    unsigned short* h0buf   = (unsigned short*)take(32768);
    unsigned short* h1buf   = (unsigned short*)take(32768);
    unsigned short* A0b     = (unsigned short*)take(8388608);
    unsigned short* hallb   = (unsigned short*)take(2097152);
    unsigned short* gmat    = (unsigned short*)take(4194304);
    float*          ph      = (float*)         take(4194304);
    float*          pe      = (float*)         take(4194304);
    float*          logitsb = (float*)         take(1048576);
    unsigned short* attb    = (unsigned short*)take(524288);
    float2*         parts   = (float2*)        take(4096000);
    float*          tgt     = (float*)         take(8192);
    unsigned short* fcWb    = (unsigned short*)take(65536000);
    size_t need = off;
    (void)in_sizes; (void)n_in;

    if (ws_size < need) {
        // Not enough scratch: fail visibly (absmax error) instead of faulting.
        hipLaunchKernelGGL(zero_out_kernel, dim3((out_size + 63) / 64), dim3(64),
                           0, stream, (float*)d_out, out_size);
        return;
    }

    hipLaunchKernelGGL(prep_kernel, dim3(62784), dim3(256), 0, stream,
                       X, enc, emb, Wih0, Whh0, Wih1, Whh1, attnW, h0, fcW,
                       wih0b, whh0b, wih1b, whh1b, whb, web, encb, enctb,
                       xsb, h0buf, h1buf, fcWb, ctrl);
    hipLaunchKernelGGL(a0_kernel, dim3(32, 32), dim3(256), 0, stream,
                       xsb, wih0b, bih0, bhh0, A0b);
    hipLaunchKernelGGL(lstm_kernel, dim3(32), dim3(512), 0, stream,
                       A0b, whh0b, wih1b, whh1b, bih1, bhh1, c0,
                       h0buf, h1buf, hallb, gmat, ctrl);
    hipLaunchKernelGGL(phpe_kernel, dim3(32, 8, 2), dim3(256), 0, stream,
                       hallb, encb, whb, web, attnb, ph, pe);
    hipLaunchKernelGGL(logits_kernel, dim3(2048), dim3(256), 0, stream,
                       ph, pe, vw, logitsb);
    hipLaunchKernelGGL(att_kernel, dim3(128), dim3(128), 0, stream,
                       logitsb, attb);
    hipLaunchKernelGGL(weighted_kernel, dim3(2, 8, 16), dim3(256), 0, stream,
                       attb, enctb, gmat);
    hipLaunchKernelGGL(fc_kernel, dim3(250, 16), dim3(256), 0, stream,
                       gmat, fcWb, fcb, parts);
    hipLaunchKernelGGL(tgt_kernel, dim3(512), dim3(256), 0, stream,
                       gmat, fcW, fcb, X, tgt);
    hipLaunchKernelGGL(finalize_kernel, dim3(1), dim3(256), 0, stream,
                       parts, tgt, X, (float*)d_out);
}